// Round 25
// baseline (120.819 us; speedup 1.0000x reference)
//
#include <hip/hip_runtime.h>

#define B_    1024
#define T_    2048
#define SEAS_ 24
#define C_    6
#define W_    1977   // T - OS - IS + 1
#define SFW_  2096   // seas_full width
#define NCH_  17     // chunks c=0..15: 120 steps; c=16: 127 steps
#define WT_   32     // w-tile per win block
#define BT_   8      // b-tile per win block
#define NWT_  62     // ceil(W_/32)
#define NBT_  128    // B_/8
#define NWIN_ (NWT_ * NBT_)   // 7936 win blocks

typedef float vf2 __attribute__((ext_vector_type(2)));
typedef float vf4 __attribute__((ext_vector_type(4)));

__device__ __forceinline__ float frcp(float x) { return __builtin_amdgcn_rcpf(x); }
__device__ __forceinline__ float getc(const float4& v, int c) {
    return c == 0 ? v.x : c == 1 ? v.y : c == 2 ? v.z : v.w;   // c is compile-time
}

template <int CTRL>
__device__ __forceinline__ float dpp_z(float v) {              // zero-fill row_shr
    return __int_as_float(__builtin_amdgcn_update_dpp(
        0, __float_as_int(v), CTRL, 0xf, 0xf, true));
}
__device__ __forceinline__ float dpp_bcast15_z(float v) {      // rows 1,3 <- lane15/47
    return __int_as_float(__builtin_amdgcn_update_dpp(
        0, __float_as_int(v), 0x142, 0xa, 0xf, false));
}
__device__ __forceinline__ float readlane_f(float v, int l) {  // l compile-time; SALU
    return __int_as_float(__builtin_amdgcn_readlane(__float_as_int(v), l));
}

// ---------------- Phase 1 block: DPP weighted Kogge-Stone over 24 lanes ----------------
__device__ __forceinline__ void scan_block(
    float xv, float& s_own, float& lev, float lev_a, float seas_b, float omb,
    float p1, float p2, float p4, float p8, float wrow, float myp)
{
    float ar  = lev_a * (xv * frcp(s_own));
    float acc = ar;
    acc = __builtin_fmaf(p1, dpp_z<0x111>(acc), acc);    // row_shr:1
    acc = __builtin_fmaf(p2, dpp_z<0x112>(acc), acc);    // row_shr:2
    acc = __builtin_fmaf(p4, dpp_z<0x114>(acc), acc);    // row_shr:4
    acc = __builtin_fmaf(p8, dpp_z<0x118>(acc), acc);    // row_shr:8
    acc = __builtin_fmaf(wrow, dpp_bcast15_z(acc), acc); // cross-row (lanes 16..23)
    float lv = __builtin_fmaf(myp, lev, acc);            // lev after own step
    float ns = __builtin_fmaf(omb, s_own, seas_b * (xv * frcp(lv)));
    s_own = ns;                                          // lanes >= 24: harmless junk
    lev = readlane_f(lv, 23);                            // block carry (step 23 = slot 0)
}

// ---------------- Phase 1: slot-parallel DPP scan (one wave/series), ~8 us -------------
__global__ __launch_bounds__(64, 1) void scan_phase1(
    const float* __restrict__ x, const float* __restrict__ lev_sms,
    const float* __restrict__ seas_sms, const float* __restrict__ seasonalities,
    const int* __restrict__ idxs, float* __restrict__ state)
{
    int b    = blockIdx.x;
    int lane = threadIdx.x;
    const float* xr = x + (size_t)b * T_;

    int id = idxs[b];
    float lev_a  = 1.0f / (1.0f + __expf(-lev_sms[id]));
    float seas_b = 1.0f / (1.0f + __expf(-seas_sms[id]));
    float oma = 1.0f - lev_a, omb = 1.0f - seas_b;

    float p1 = oma, p2 = p1 * p1, p4 = p2 * p2, p8 = p4 * p4, p16 = p8 * p8;
    int lp1 = lane + 1;
    float myp = ((lp1 & 1)  ? p1  : 1.0f) * ((lp1 & 2)  ? p2  : 1.0f)
              * ((lp1 & 4)  ? p4  : 1.0f) * ((lp1 & 8)  ? p8  : 1.0f)
              * ((lp1 & 16) ? p16 : 1.0f);           // oma^(lane+1)
    int e = lane - 15;
    float wrow = 0.0f;
    if (e > 0) {
        wrow = ((e & 1) ? p1 : 1.0f) * ((e & 2) ? p2 : 1.0f)
             * ((e & 4) ? p4 : 1.0f) * ((e & 8) ? p8 : 1.0f);   // oma^(lane-15)
    }

    int pos_own = (lane + 1 < 24) ? (lane + 1) : 0;
    float s_own = 1.0f;
    if (lane < 24) s_own = __expf(seasonalities[id * SEAS_ + pos_own]);

    float s0  = readlane_f(s_own, 23);
    float lev = xr[0] * frcp(s0);                    // lev0

    float xA0 = xr[1 +   0 + lane], xA1 = xr[1 +  24 + lane], xA2 = xr[1 +  48 + lane],
          xA3 = xr[1 +  72 + lane], xA4 = xr[1 +  96 + lane];
    float xB0 = xr[1 + 120 + lane], xB1 = xr[1 + 144 + lane], xB2 = xr[1 + 168 + lane],
          xB3 = xr[1 + 192 + lane], xB4 = xr[1 + 216 + lane];

    for (int g = 0; g < 16; g += 2) {
        int baseA = 1 + 5 * (g + 2) * 24 + lane;
        scan_block(xA0, s_own, lev, lev_a, seas_b, omb, p1, p2, p4, p8, wrow, myp);
        { int t = baseA;      xA0 = xr[t > 2047 ? 2047 : t]; }
        scan_block(xA1, s_own, lev, lev_a, seas_b, omb, p1, p2, p4, p8, wrow, myp);
        { int t = baseA + 24; xA1 = xr[t > 2047 ? 2047 : t]; }
        scan_block(xA2, s_own, lev, lev_a, seas_b, omb, p1, p2, p4, p8, wrow, myp);
        { int t = baseA + 48; xA2 = xr[t > 2047 ? 2047 : t]; }
        scan_block(xA3, s_own, lev, lev_a, seas_b, omb, p1, p2, p4, p8, wrow, myp);
        { int t = baseA + 72; xA3 = xr[t > 2047 ? 2047 : t]; }
        scan_block(xA4, s_own, lev, lev_a, seas_b, omb, p1, p2, p4, p8, wrow, myp);
        { int t = baseA + 96; xA4 = xr[t > 2047 ? 2047 : t]; }
        {   float* st = state + ((size_t)g * B_ + b) * 25;       // t = 120(g+1)
            if (lane < 24) st[pos_own] = s_own;
            if (lane == 24) st[24] = lev;
        }
        int baseB = 1 + 5 * (g + 3) * 24 + lane;
        scan_block(xB0, s_own, lev, lev_a, seas_b, omb, p1, p2, p4, p8, wrow, myp);
        { int t = baseB;      xB0 = xr[t > 2047 ? 2047 : t]; }
        scan_block(xB1, s_own, lev, lev_a, seas_b, omb, p1, p2, p4, p8, wrow, myp);
        { int t = baseB + 24; xB1 = xr[t > 2047 ? 2047 : t]; }
        scan_block(xB2, s_own, lev, lev_a, seas_b, omb, p1, p2, p4, p8, wrow, myp);
        { int t = baseB + 48; xB2 = xr[t > 2047 ? 2047 : t]; }
        scan_block(xB3, s_own, lev, lev_a, seas_b, omb, p1, p2, p4, p8, wrow, myp);
        { int t = baseB + 72; xB3 = xr[t > 2047 ? 2047 : t]; }
        scan_block(xB4, s_own, lev, lev_a, seas_b, omb, p1, p2, p4, p8, wrow, myp);
        { int t = baseB + 96; xB4 = xr[t > 2047 ? 2047 : t]; }
        {   float* st = state + ((size_t)(g + 1) * B_ + b) * 25; // t = 120(g+2)
            if (lane < 24) st[pos_own] = s_own;
            if (lane == 24) st[24] = lev;
        }
    }
}

// One 24-step block; writes levT global col + LDS tile rows (lev, ns). ILP-exposed.
__device__ __forceinline__ void es_block24_lds(
    const float4* __restrict__ xv, float* __restrict__ s,
    float lev_a, float oma, float seas_b, float omb, float& lev,
    float* __restrict__ levp, float* __restrict__ lrow, float* __restrict__ nrow)
{
    float ar[24], lv[24];
    #pragma unroll
    for (int j = 0; j < 24; ++j) {
        const int e = j + 1, pos = (j + 1 < 24) ? (j + 1) : 0;
        ar[j] = lev_a * (getc(xv[e >> 2], e & 3) * frcp(s[pos]));
    }
    #pragma unroll
    for (int j = 0; j < 24; ++j) {                   // serial lev chain
        lev = __builtin_fmaf(oma, lev, ar[j]);
        lv[j] = lev;
    }
    #pragma unroll
    for (int j = 0; j < 24; ++j) {                   // independent seasonal updates
        const int e = j + 1, pos = (j + 1 < 24) ? (j + 1) : 0;
        float xi = getc(xv[e >> 2], e & 3);
        float ns = __builtin_fmaf(omb, s[pos], seas_b * (xi * frcp(lv[j])));
        s[pos] = ns;
        levp[(size_t)j * B_] = lv[j];                // levT [t][b] (for msld)
        lrow[j] = lv[j];                             // LDS tiles (for b-major writes)
        nrow[j] = ns;
    }
}

// ---------------- Phase 2 (MEASUREMENT BUILD: x4 in-kernel repeat) ---------------------
// Idempotent: each rep recomputes and rewrites identical values; opaque zero blocks
// cross-rep hoisting. phase2_per_rep = (dur_us_total - 81.6) / 3.
__global__ __launch_bounds__(64, 1) void scan_phase2(
    const float* __restrict__ x, const float* __restrict__ lev_sms,
    const float* __restrict__ seas_sms, const float* __restrict__ seasonalities,
    const int* __restrict__ idxs, const float* __restrict__ state,
    float* __restrict__ levT, float* __restrict__ out_levs,
    float* __restrict__ out_seas)
{
    __shared__ float lev_lds[64][129];
    __shared__ float ns_lds[64][129];
    int tid = threadIdx.x;

    #pragma unroll 1
    for (int rep = 0; rep < 4; ++rep) {
        int zero;                                        // opaque 0, fresh each rep
        asm volatile("v_mov_b32 %0, 0" : "=v"(zero));
        int b = blockIdx.x * 64 + tid + zero;
        int c = blockIdx.y;
        const float4* xr4 = (const float4*)(x + (size_t)b * T_);

        int id = idxs[b];
        float lev_a  = 1.0f / (1.0f + __expf(-lev_sms[id]));
        float seas_b = 1.0f / (1.0f + __expf(-seas_sms[id]));
        float oma = 1.0f - lev_a, omb = 1.0f - seas_b;

        float s[SEAS_];
        float lev;
        if (c == 0) {
            #pragma unroll
            for (int j = 0; j < SEAS_; ++j) s[j] = __expf(seasonalities[id * SEAS_ + j]);
            #pragma unroll
            for (int j = 0; j < SEAS_; ++j) ns_lds[tid][j] = s[j];
            ns_lds[tid][24] = s[0];
            __syncthreads();
            for (int r = 0; r < 64; ++r) {
                int bb = blockIdx.x * 64 + r;
                if (tid < 25) out_seas[(size_t)bb * SFW_ + tid] = ns_lds[r][tid];
            }
            __syncthreads();
            lev = getc(xr4[0], 0) * frcp(s[0]);          // lev0
            levT[b] = lev;                               // row 0 (msld)
            out_levs[(size_t)b * T_] = lev;              // t = 0
        } else {
            const float* st = state + ((size_t)(c - 1) * B_ + b) * 25;
            #pragma unroll
            for (int j = 0; j < SEAS_; ++j) s[j] = st[j];
            lev = st[24];
        }

        float4 xv[7], xn[7];
        const float4* base0 = xr4 + 30 * c;              // t = 120c ..
        #pragma unroll
        for (int q = 0; q < 7; ++q) xv[q] = base0[q];

        float* levp = levT + (size_t)(120 * c + 1) * B_ + b;

        #pragma unroll
        for (int kb = 0; kb < 5; ++kb) {                 // 5 blocks of 24 steps
            const float4* nb = xr4 + 30 * c + 6 * (kb + 1);
            if (c == NCH_ - 1 && kb == 4) {
                xn[0] = nb[0]; xn[1] = nb[1];
            } else {
                #pragma unroll
                for (int q = 0; q < 7; ++q) xn[q] = nb[q];
            }
            es_block24_lds(xv, s, lev_a, oma, seas_b, omb, lev, levp,
                           &lev_lds[tid][kb * 24], &ns_lds[tid][kb * 24]);
            levp += (size_t)24 * B_;
            #pragma unroll
            for (int q = 0; q < 7; ++q) xv[q] = xn[q];
        }
        if (c == NCH_ - 1) {                             // tail t = 2041..2047
            #pragma unroll
            for (int j = 0; j < 7; ++j) {
                const int e = j + 1, pos = j + 1;
                float xi    = getc(xv[e >> 2], e & 3);
                float ratio = xi * frcp(s[pos]);
                float nl    = __builtin_fmaf(oma, lev, lev_a * ratio);
                float ns    = __builtin_fmaf(omb, s[pos], seas_b * (xi * frcp(nl)));
                s[pos] = ns;
                lev = nl;
                levp[0] = nl;  levp += B_;
                lev_lds[tid][120 + j] = nl;
                ns_lds[tid][120 + j]  = ns;
            }
        }

        __syncthreads();
        int tb = 120 * c + 1;
        int NT = (c == NCH_ - 1) ? 127 : 120;
        for (int r = 0; r < 64; ++r) {
            int bb = blockIdx.x * 64 + r;
            float* ol = out_levs + (size_t)bb * T_ + tb;
            float* os = out_seas + (size_t)bb * SFW_ + tb + 24;
            ol[tid] = lev_lds[r][tid];
            os[tid] = ns_lds[r][tid];
            int t2 = tid + 64;
            if (t2 < NT) {
                ol[t2] = lev_lds[r][t2];
                os[t2] = ns_lds[r][t2];
            }
            if (c == NCH_ - 1 && tid < 24)               // seasonal tail repeat
                out_seas[(size_t)bb * SFW_ + 2072 + tid] = ns_lds[r][103 + tid];
        }
        __syncthreads();                                 // safe re-entry for next rep
    }
}

// ---------------- mega: tiled win (32w x 8b per block, LDS-staged) + msld --------------
__global__ __launch_bounds__(256) void mega_kernel(
    const float* __restrict__ x, const float* __restrict__ levs,
    const float* __restrict__ seasF, const float* __restrict__ info_cat,
    const float* __restrict__ levT, vf4* __restrict__ out4,
    float* __restrict__ out_msld)
{
    int bid = blockIdx.x;
    int tid = threadIdx.x;
    if (bid < NWIN_) {                               // ---------------- win role
        __shared__ float x_t[BT_][57];               // t in [w0, w0+55]
        __shared__ float s_t[BT_][57];
        __shared__ float l_t[BT_][33];               // levs[b][w0+23+w], w in [0,32)
        __shared__ float ic[BT_][8];                 // info_cat (6 used)
        __shared__ __align__(16) vf2 ob[WT_][120];   // out staging: 32 w x 120 f2

        int wt = bid / NBT_;
        int bt = bid - wt * NBT_;
        int w0 = wt * WT_;                           // multiple of 32 -> f4-aligned
        int b0 = bt * BT_;

        // ---- load phase ----
        if (tid < 112) {                             // x: 8 rows x 14 f4
            int b = tid / 14, q = tid - b * 14;
            vf4 v = ((const vf4*)(x + (size_t)(b0 + b) * T_ + w0))[q];
            x_t[b][4 * q + 0] = v.x; x_t[b][4 * q + 1] = v.y;
            x_t[b][4 * q + 2] = v.z; x_t[b][4 * q + 3] = v.w;
        } else if (tid < 224) {                      // seas: 8 rows x 14 f4
            int t2 = tid - 112;
            int b = t2 / 14, q = t2 - b * 14;
            vf4 v = ((const vf4*)(seasF + (size_t)(b0 + b) * SFW_ + w0))[q];
            s_t[b][4 * q + 0] = v.x; s_t[b][4 * q + 1] = v.y;
            s_t[b][4 * q + 2] = v.z; s_t[b][4 * q + 3] = v.w;
        }
        {                                            // levs: 8 rows x 32 (scalar)
            int b = tid >> 5, w = tid & 31;
            l_t[b][w] = levs[(size_t)(b0 + b) * T_ + w0 + w + 23];
        }
        if (tid < 48) {                              // info_cat: 8 x 6
            int b = tid / 6, cc = tid - b * 6;
            ic[b][cc] = info_cat[(b0 + b) * C_ + cc];
        }
        __syncthreads();

        // ---- compute phase: one (w, b) pair per thread ----
        int w_l = tid >> 3, b_l = tid & 7;
        if (w0 + w_l < W_) {
            float inv = frcp(l_t[b_l][w_l]);
            vf2* obr = &ob[w_l][b_l * 15];
            #pragma unroll
            for (int j = 0; j < 12; ++j) {
                int t = w_l + 2 * j;
                vf2 v;
                v.x = x_t[b_l][t]     * frcp(s_t[b_l][t])     * inv;
                v.y = x_t[b_l][t + 1] * frcp(s_t[b_l][t + 1]) * inv;
                obr[j] = v;
            }
            #pragma unroll
            for (int j = 12; j < 15; ++j) {
                int cc = 2 * (j - 12);
                vf2 v;
                v.x = ic[b_l][cc];
                v.y = ic[b_l][cc + 1];
                obr[j] = v;
            }
        }
        __syncthreads();

        // ---- store phase: 1920 contiguous f4 per block, nontemporal ----
        const vf4* obf4 = (const vf4*)ob;            // row w_l = f4 [60*w_l, 60*w_l+60)
        #pragma unroll
        for (int k = 0; k < 8; ++k) {
            int g = tid + k * 256;
            if (g < 1920) {
                int w_l2 = g / 60, q = g - w_l2 * 60;
                if (w0 + w_l2 < W_) {
                    __builtin_nontemporal_store(
                        obf4[g], &out4[(size_t)(w0 + w_l2) * 7680 + bt * 60 + q]);
                }
            }
        }
    } else {                                         // ---------------- msld role
        int i = bid - NWIN_;                         // 0..2045
        const float* r0 = levT + (size_t)i * B_;
        float ssum = 0.0f;
        #pragma unroll
        for (int r = 0; r < 4; ++r) {
            int b = tid + 256 * r;
            float l0 = __logf(r0[b]);
            float l1 = __logf(r0[b + B_]);
            float l2 = __logf(r0[b + 2 * B_]);
            float d  = l2 - 2.0f * l1 + l0;
            ssum = __builtin_fmaf(d, d, ssum);
        }
        #pragma unroll
        for (int off = 32; off > 0; off >>= 1) ssum += __shfl_down(ssum, off);
        __shared__ float partial[4];
        int wid = tid >> 6;
        if ((tid & 63) == 0) partial[wid] = ssum;
        __syncthreads();
        if (tid == 0)
            out_msld[i] = (partial[0] + partial[1] + partial[2] + partial[3])
                          * (1.0f / 1024.0f);
    }
}

extern "C" void kernel_launch(void* const* d_in, const int* in_sizes, int n_in,
                              void* d_out, int out_size, void* d_ws, size_t ws_size,
                              hipStream_t stream)
{
    const float* train    = (const float*)d_in[0];
    const float* info_cat = (const float*)d_in[3];
    const float* lev_sms  = (const float*)d_in[4];
    const float* seas_sms = (const float*)d_in[5];
    const float* seasonal = (const float*)d_in[6];
    const int*   idxs     = (const int*)d_in[7];

    float* out      = (float*)d_out;
    float* out_ib   = out;                               // W*B*30
    float* out_levs = out + (size_t)W_ * B_ * 30;        // B*2048
    float* out_seas = out_levs + (size_t)B_ * T_;        // B*2096
    float* out_msld = out_seas + (size_t)B_ * SFW_;      // 2046

    float* ws   = (float*)d_ws;
    float* levT = ws;                                    // 2048*1024 floats

    // Exact boundary states in the head of out_ib: written by phase1, read by phase2,
    // later overwritten by mega's win blocks (stream-ordered, race-free).
    float* state = out_ib;                               // 16*1024*25 floats (1.6 MB)

    scan_phase1<<<B_, 64, 0, stream>>>(train, lev_sms, seas_sms, seasonal, idxs, state);

    scan_phase2<<<dim3(B_ / 64, NCH_), 64, 0, stream>>>(train, lev_sms, seas_sms,
                                                        seasonal, idxs, state,
                                                        levT, out_levs, out_seas);

    mega_kernel<<<NWIN_ + 2046, 256, 0, stream>>>(
        train, out_levs, out_seas, info_cat, levT, (vf4*)out_ib, out_msld);
}

// Round 26
// 87.714 us; speedup vs baseline: 1.3774x; 1.3774x over previous
//
#include <hip/hip_runtime.h>

#define B_    1024
#define T_    2048
#define SEAS_ 24
#define C_    6
#define W_    1977   // T - OS - IS + 1
#define SFW_  2096   // seas_full width
#define CH2_  48     // phase2 chunk length (multiple of 24)
#define NCH_  43     // chunks c=0..41: 48 steps; c=42: 31 steps (t=2017..2047)
#define WT_   32     // w-tile per win block
#define BT_   8      // b-tile per win block
#define NWT_  62     // ceil(W_/32)
#define NBT_  128    // B_/8
#define NWIN_ (NWT_ * NBT_)   // 7936 win blocks

typedef float vf2 __attribute__((ext_vector_type(2)));
typedef float vf4 __attribute__((ext_vector_type(4)));

__device__ __forceinline__ float frcp(float x) { return __builtin_amdgcn_rcpf(x); }
__device__ __forceinline__ float getc(const float4& v, int c) {
    return c == 0 ? v.x : c == 1 ? v.y : c == 2 ? v.z : v.w;   // c is compile-time
}

template <int CTRL>
__device__ __forceinline__ float dpp_z(float v) {              // zero-fill row_shr
    return __int_as_float(__builtin_amdgcn_update_dpp(
        0, __float_as_int(v), CTRL, 0xf, 0xf, true));
}
__device__ __forceinline__ float dpp_bcast15_z(float v) {      // rows 1,3 <- lane15/47
    return __int_as_float(__builtin_amdgcn_update_dpp(
        0, __float_as_int(v), 0x142, 0xa, 0xf, false));
}
__device__ __forceinline__ float readlane_f(float v, int l) {  // l compile-time; SALU
    return __int_as_float(__builtin_amdgcn_readlane(__float_as_int(v), l));
}

// ---------------- Phase 1 block: DPP weighted Kogge-Stone over 24 lanes ----------------
__device__ __forceinline__ void scan_block(
    float xv, float& s_own, float& lev, float lev_a, float seas_b, float omb,
    float p1, float p2, float p4, float p8, float wrow, float myp)
{
    float ar  = lev_a * (xv * frcp(s_own));
    float acc = ar;
    acc = __builtin_fmaf(p1, dpp_z<0x111>(acc), acc);    // row_shr:1
    acc = __builtin_fmaf(p2, dpp_z<0x112>(acc), acc);    // row_shr:2
    acc = __builtin_fmaf(p4, dpp_z<0x114>(acc), acc);    // row_shr:4
    acc = __builtin_fmaf(p8, dpp_z<0x118>(acc), acc);    // row_shr:8
    acc = __builtin_fmaf(wrow, dpp_bcast15_z(acc), acc); // cross-row (lanes 16..23)
    float lv = __builtin_fmaf(myp, lev, acc);            // lev after own step
    float ns = __builtin_fmaf(omb, s_own, seas_b * (xv * frcp(lv)));
    s_own = ns;                                          // lanes >= 24: harmless junk
    lev = readlane_f(lv, 23);                            // block carry (step 23 = slot 0)
}

// ---------------- Phase 1: slot-parallel DPP scan; saves state every 48 steps ----------
// 84 blocks (t = 1..2016); state[c] = (s, lev) after t = 48(c+1), c = 0..41.
__global__ __launch_bounds__(64, 1) void scan_phase1(
    const float* __restrict__ x, const float* __restrict__ lev_sms,
    const float* __restrict__ seas_sms, const float* __restrict__ seasonalities,
    const int* __restrict__ idxs, float* __restrict__ state)
{
    int b    = blockIdx.x;
    int lane = threadIdx.x;
    const float* xr = x + (size_t)b * T_;

    int id = idxs[b];
    float lev_a  = 1.0f / (1.0f + __expf(-lev_sms[id]));
    float seas_b = 1.0f / (1.0f + __expf(-seas_sms[id]));
    float oma = 1.0f - lev_a, omb = 1.0f - seas_b;

    float p1 = oma, p2 = p1 * p1, p4 = p2 * p2, p8 = p4 * p4, p16 = p8 * p8;
    int lp1 = lane + 1;
    float myp = ((lp1 & 1)  ? p1  : 1.0f) * ((lp1 & 2)  ? p2  : 1.0f)
              * ((lp1 & 4)  ? p4  : 1.0f) * ((lp1 & 8)  ? p8  : 1.0f)
              * ((lp1 & 16) ? p16 : 1.0f);           // oma^(lane+1)
    int e = lane - 15;
    float wrow = 0.0f;
    if (e > 0) {
        wrow = ((e & 1) ? p1 : 1.0f) * ((e & 2) ? p2 : 1.0f)
             * ((e & 4) ? p4 : 1.0f) * ((e & 8) ? p8 : 1.0f);   // oma^(lane-15)
    }

    int pos_own = (lane + 1 < 24) ? (lane + 1) : 0;
    float s_own = 1.0f;
    if (lane < 24) s_own = __expf(seasonalities[id * SEAS_ + pos_own]);

    float s0  = readlane_f(s_own, 23);
    float lev = xr[0] * frcp(s0);                    // lev0

    float xA0 = xr[1 +  0 + lane], xA1 = xr[1 + 24 + lane];   // blocks 0,1
    float xB0 = xr[1 + 48 + lane], xB1 = xr[1 + 72 + lane];   // blocks 2,3

    for (int p = 0; p < 21; ++p) {                   // 21 x 4 blocks = 84 blocks
        int baseA = 1 + (4 * p + 4) * 24 + lane;     // refill A <- blocks 4p+4, 4p+5
        scan_block(xA0, s_own, lev, lev_a, seas_b, omb, p1, p2, p4, p8, wrow, myp);
        { int t = baseA;      xA0 = xr[t > 2047 ? 2047 : t]; }
        scan_block(xA1, s_own, lev, lev_a, seas_b, omb, p1, p2, p4, p8, wrow, myp);
        { int t = baseA + 24; xA1 = xr[t > 2047 ? 2047 : t]; }
        {   float* st = state + ((size_t)(2 * p) * B_ + b) * 25;     // after t=48(2p+1)
            if (lane < 24) st[pos_own] = s_own;
            if (lane == 24) st[24] = lev;
        }
        int baseB = 1 + (4 * p + 6) * 24 + lane;     // refill B <- blocks 4p+6, 4p+7
        scan_block(xB0, s_own, lev, lev_a, seas_b, omb, p1, p2, p4, p8, wrow, myp);
        { int t = baseB;      xB0 = xr[t > 2047 ? 2047 : t]; }
        scan_block(xB1, s_own, lev, lev_a, seas_b, omb, p1, p2, p4, p8, wrow, myp);
        { int t = baseB + 24; xB1 = xr[t > 2047 ? 2047 : t]; }
        {   float* st = state + ((size_t)(2 * p + 1) * B_ + b) * 25; // after t=48(2p+2)
            if (lane < 24) st[pos_own] = s_own;
            if (lane == 24) st[24] = lev;
        }
    }
}

// One 24-step block; writes levT global col + LDS tile rows (lev, ns). ILP-exposed.
__device__ __forceinline__ void es_block24_lds(
    const float4* __restrict__ xv, float* __restrict__ s,
    float lev_a, float oma, float seas_b, float omb, float& lev,
    float* __restrict__ levp, float* __restrict__ lrow, float* __restrict__ nrow)
{
    float ar[24], lv[24];
    #pragma unroll
    for (int j = 0; j < 24; ++j) {
        const int e = j + 1, pos = (j + 1 < 24) ? (j + 1) : 0;
        ar[j] = lev_a * (getc(xv[e >> 2], e & 3) * frcp(s[pos]));
    }
    #pragma unroll
    for (int j = 0; j < 24; ++j) {                   // serial lev chain
        lev = __builtin_fmaf(oma, lev, ar[j]);
        lv[j] = lev;
    }
    #pragma unroll
    for (int j = 0; j < 24; ++j) {                   // independent seasonal updates
        const int e = j + 1, pos = (j + 1 < 24) ? (j + 1) : 0;
        float xi = getc(xv[e >> 2], e & 3);
        float ns = __builtin_fmaf(omb, s[pos], seas_b * (xi * frcp(lv[j])));
        s[pos] = ns;
        levp[(size_t)j * B_] = lv[j];                // levT [t][b] (for msld)
        lrow[j] = lv[j];                             // LDS tiles (for b-major writes)
        nrow[j] = ns;
    }
}

// ---------------- Phase 2: 43 exact 48-step chunks; writes levT + out_levs/out_seas ----
// Tiles [64][57] (57 coprime 32 -> conflict-free column writes). Chunk c covers
// t in [48c+1, 48c+48] (c=42: t=2017..2047, 31 steps). Col j = t - 48c.
__global__ __launch_bounds__(64, 1) void scan_phase2(
    const float* __restrict__ x, const float* __restrict__ lev_sms,
    const float* __restrict__ seas_sms, const float* __restrict__ seasonalities,
    const int* __restrict__ idxs, const float* __restrict__ state,
    float* __restrict__ levT, float* __restrict__ out_levs,
    float* __restrict__ out_seas)
{
    __shared__ float lev_lds[64][57];
    __shared__ float ns_lds[64][57];
    int tid = threadIdx.x;
    int b = blockIdx.x * 64 + tid;
    int c = blockIdx.y;
    const float4* xr4 = (const float4*)(x + (size_t)b * T_);

    int id = idxs[b];
    float lev_a  = 1.0f / (1.0f + __expf(-lev_sms[id]));
    float seas_b = 1.0f / (1.0f + __expf(-seas_sms[id]));
    float oma = 1.0f - lev_a, omb = 1.0f - seas_b;

    float s[SEAS_];
    float lev;
    if (c == 0) {
        #pragma unroll
        for (int j = 0; j < SEAS_; ++j) s[j] = __expf(seasonalities[id * SEAS_ + j]);
        // out_seas head (u < 25): stage in ns_lds cols 0..24, write coalesced
        #pragma unroll
        for (int j = 0; j < SEAS_; ++j) ns_lds[tid][j] = s[j];
        ns_lds[tid][24] = s[0];
        __syncthreads();
        for (int r = 0; r < 64; ++r) {
            int bb = blockIdx.x * 64 + r;
            if (tid < 25) out_seas[(size_t)bb * SFW_ + tid] = ns_lds[r][tid];
        }
        __syncthreads();
        lev = getc(xr4[0], 0) * frcp(s[0]);              // lev0
        levT[b] = lev;                                   // row 0 (msld)
        out_levs[(size_t)b * T_] = lev;                  // t = 0
    } else {
        const float* st = state + ((size_t)(c - 1) * B_ + b) * 25;
        #pragma unroll
        for (int j = 0; j < SEAS_; ++j) s[j] = st[j];
        lev = st[24];
    }

    float4 xv[7], xn[7];
    const float4* base0 = xr4 + 12 * c;                  // quad for t = 48c
    #pragma unroll
    for (int q = 0; q < 7; ++q) xv[q] = base0[q];

    float* levp = levT + (size_t)(48 * c + 1) * B_ + b;

    // ---- block kb = 0: t = 48c+1 .. 48c+24, cols 1..24 ----
    if (c == NCH_ - 1) {                                 // tail prefetch: quads 510,511
        xn[0] = base0[6]; xn[1] = base0[7];
    } else {                                             // next block: quads 12c+6..+12
        #pragma unroll
        for (int q = 0; q < 7; ++q) xn[q] = (base0 + 6)[q];
    }
    es_block24_lds(xv, s, lev_a, oma, seas_b, omb, lev, levp,
                   &lev_lds[tid][1], &ns_lds[tid][1]);
    levp += (size_t)24 * B_;
    #pragma unroll
    for (int q = 0; q < 7; ++q) xv[q] = xn[q];

    if (c < NCH_ - 1) {                                  // block kb = 1: cols 25..48
        es_block24_lds(xv, s, lev_a, oma, seas_b, omb, lev, levp,
                       &lev_lds[tid][25], &ns_lds[tid][25]);
    } else {                                             // tail: t = 2041..2047, cols 25..31
        #pragma unroll
        for (int j = 0; j < 7; ++j) {
            const int e = j + 1, pos = j + 1;
            float xi    = getc(xv[e >> 2], e & 3);
            float ratio = xi * frcp(s[pos]);
            float nl    = __builtin_fmaf(oma, lev, lev_a * ratio);
            float ns    = __builtin_fmaf(omb, s[pos], seas_b * (xi * frcp(nl)));
            s[pos] = ns;
            lev = nl;
            levp[0] = nl;  levp += B_;
            lev_lds[tid][25 + j] = nl;
            ns_lds[tid][25 + j]  = ns;
        }
    }

    // ---- coalesced b-major write-out ----
    __syncthreads();
    int tb = 48 * c + 1;
    int NT = (c == NCH_ - 1) ? 31 : 48;
    for (int r = 0; r < 64; ++r) {
        int bb = blockIdx.x * 64 + r;
        if (tid < NT) {
            out_levs[(size_t)bb * T_ + tb + tid]        = lev_lds[r][1 + tid];
            out_seas[(size_t)bb * SFW_ + tb + 24 + tid] = ns_lds[r][1 + tid];
        }
        if (c == NCH_ - 1 && tid < 24)                   // seasonal tail repeat
            out_seas[(size_t)bb * SFW_ + 2072 + tid] = ns_lds[r][8 + tid];
    }
}

// ---------------- mega: tiled win (32w x 8b per block, LDS-staged) + msld --------------
__global__ __launch_bounds__(256) void mega_kernel(
    const float* __restrict__ x, const float* __restrict__ levs,
    const float* __restrict__ seasF, const float* __restrict__ info_cat,
    const float* __restrict__ levT, vf4* __restrict__ out4,
    float* __restrict__ out_msld)
{
    int bid = blockIdx.x;
    int tid = threadIdx.x;
    if (bid < NWIN_) {                               // ---------------- win role
        __shared__ float x_t[BT_][57];               // t in [w0, w0+55]
        __shared__ float s_t[BT_][57];
        __shared__ float l_t[BT_][33];               // levs[b][w0+23+w], w in [0,32)
        __shared__ float ic[BT_][8];                 // info_cat (6 used)
        __shared__ __align__(16) vf2 ob[WT_][120];   // out staging: 32 w x 120 f2

        int wt = bid / NBT_;
        int bt = bid - wt * NBT_;
        int w0 = wt * WT_;                           // multiple of 32 -> f4-aligned
        int b0 = bt * BT_;

        // ---- load phase ----
        if (tid < 112) {                             // x: 8 rows x 14 f4
            int b = tid / 14, q = tid - b * 14;
            vf4 v = ((const vf4*)(x + (size_t)(b0 + b) * T_ + w0))[q];
            x_t[b][4 * q + 0] = v.x; x_t[b][4 * q + 1] = v.y;
            x_t[b][4 * q + 2] = v.z; x_t[b][4 * q + 3] = v.w;
        } else if (tid < 224) {                      // seas: 8 rows x 14 f4
            int t2 = tid - 112;
            int b = t2 / 14, q = t2 - b * 14;
            vf4 v = ((const vf4*)(seasF + (size_t)(b0 + b) * SFW_ + w0))[q];
            s_t[b][4 * q + 0] = v.x; s_t[b][4 * q + 1] = v.y;
            s_t[b][4 * q + 2] = v.z; s_t[b][4 * q + 3] = v.w;
        }
        {                                            // levs: 8 rows x 32 (scalar)
            int b = tid >> 5, w = tid & 31;
            l_t[b][w] = levs[(size_t)(b0 + b) * T_ + w0 + w + 23];
        }
        if (tid < 48) {                              // info_cat: 8 x 6
            int b = tid / 6, cc = tid - b * 6;
            ic[b][cc] = info_cat[(b0 + b) * C_ + cc];
        }
        __syncthreads();

        // ---- compute phase: one (w, b) pair per thread ----
        int w_l = tid >> 3, b_l = tid & 7;
        if (w0 + w_l < W_) {
            float inv = frcp(l_t[b_l][w_l]);
            vf2* obr = &ob[w_l][b_l * 15];
            #pragma unroll
            for (int j = 0; j < 12; ++j) {
                int t = w_l + 2 * j;
                vf2 v;
                v.x = x_t[b_l][t]     * frcp(s_t[b_l][t])     * inv;
                v.y = x_t[b_l][t + 1] * frcp(s_t[b_l][t + 1]) * inv;
                obr[j] = v;
            }
            #pragma unroll
            for (int j = 12; j < 15; ++j) {
                int cc = 2 * (j - 12);
                vf2 v;
                v.x = ic[b_l][cc];
                v.y = ic[b_l][cc + 1];
                obr[j] = v;
            }
        }
        __syncthreads();

        // ---- store phase: 1920 contiguous f4 per block, nontemporal ----
        const vf4* obf4 = (const vf4*)ob;            // row w_l = f4 [60*w_l, 60*w_l+60)
        #pragma unroll
        for (int k = 0; k < 8; ++k) {
            int g = tid + k * 256;
            if (g < 1920) {
                int w_l2 = g / 60, q = g - w_l2 * 60;
                if (w0 + w_l2 < W_) {
                    __builtin_nontemporal_store(
                        obf4[g], &out4[(size_t)(w0 + w_l2) * 7680 + bt * 60 + q]);
                }
            }
        }
    } else {                                         // ---------------- msld role
        int i = bid - NWIN_;                         // 0..2045
        const float* r0 = levT + (size_t)i * B_;
        float ssum = 0.0f;
        #pragma unroll
        for (int r = 0; r < 4; ++r) {
            int b = tid + 256 * r;
            float l0 = __logf(r0[b]);
            float l1 = __logf(r0[b + B_]);
            float l2 = __logf(r0[b + 2 * B_]);
            float d  = l2 - 2.0f * l1 + l0;
            ssum = __builtin_fmaf(d, d, ssum);
        }
        #pragma unroll
        for (int off = 32; off > 0; off >>= 1) ssum += __shfl_down(ssum, off);
        __shared__ float partial[4];
        int wid = tid >> 6;
        if ((tid & 63) == 0) partial[wid] = ssum;
        __syncthreads();
        if (tid == 0)
            out_msld[i] = (partial[0] + partial[1] + partial[2] + partial[3])
                          * (1.0f / 1024.0f);
    }
}

extern "C" void kernel_launch(void* const* d_in, const int* in_sizes, int n_in,
                              void* d_out, int out_size, void* d_ws, size_t ws_size,
                              hipStream_t stream)
{
    const float* train    = (const float*)d_in[0];
    const float* info_cat = (const float*)d_in[3];
    const float* lev_sms  = (const float*)d_in[4];
    const float* seas_sms = (const float*)d_in[5];
    const float* seasonal = (const float*)d_in[6];
    const int*   idxs     = (const int*)d_in[7];

    float* out      = (float*)d_out;
    float* out_ib   = out;                               // W*B*30
    float* out_levs = out + (size_t)W_ * B_ * 30;        // B*2048
    float* out_seas = out_levs + (size_t)B_ * T_;        // B*2096
    float* out_msld = out_seas + (size_t)B_ * SFW_;      // 2046

    float* ws   = (float*)d_ws;
    float* levT = ws;                                    // 2048*1024 floats

    // Exact boundary states in the head of out_ib: written by phase1, read by phase2,
    // later overwritten by mega's win blocks (stream-ordered, race-free).
    float* state = out_ib;                               // 42*1024*25 floats (4.3 MB)

    scan_phase1<<<B_, 64, 0, stream>>>(train, lev_sms, seas_sms, seasonal, idxs, state);

    scan_phase2<<<dim3(B_ / 64, NCH_), 64, 0, stream>>>(train, lev_sms, seas_sms,
                                                        seasonal, idxs, state,
                                                        levT, out_levs, out_seas);

    mega_kernel<<<NWIN_ + 2046, 256, 0, stream>>>(
        train, out_levs, out_seas, info_cat, levT, (vf4*)out_ib, out_msld);
}

// Round 27
// 81.575 us; speedup vs baseline: 1.4811x; 1.0752x over previous
//
#include <hip/hip_runtime.h>

#define B_    1024
#define T_    2048
#define SEAS_ 24
#define C_    6
#define W_    1977   // T - OS - IS + 1
#define SFW_  2096   // seas_full width
#define NCH_  17     // chunks c=0..15: 120 steps; c=16: 127 steps
#define WT_   32     // w-tile per win block
#define BT_   8      // b-tile per win block
#define NWT_  62     // ceil(W_/32)
#define NBT_  128    // B_/8
#define NWIN_ (NWT_ * NBT_)   // 7936 win blocks

typedef float vf2 __attribute__((ext_vector_type(2)));
typedef float vf4 __attribute__((ext_vector_type(4)));

__device__ __forceinline__ float frcp(float x) { return __builtin_amdgcn_rcpf(x); }
__device__ __forceinline__ float getc(const float4& v, int c) {
    return c == 0 ? v.x : c == 1 ? v.y : c == 2 ? v.z : v.w;   // c is compile-time
}

template <int CTRL>
__device__ __forceinline__ float dpp_z(float v) {              // zero-fill row_shr
    return __int_as_float(__builtin_amdgcn_update_dpp(
        0, __float_as_int(v), CTRL, 0xf, 0xf, true));
}
__device__ __forceinline__ float dpp_bcast15_z(float v) {      // rows 1,3 <- lane15/47
    return __int_as_float(__builtin_amdgcn_update_dpp(
        0, __float_as_int(v), 0x142, 0xa, 0xf, false));
}
__device__ __forceinline__ float readlane_f(float v, int l) {  // l compile-time; SALU
    return __int_as_float(__builtin_amdgcn_readlane(__float_as_int(v), l));
}

// ---------------- Phase 1 block: DPP weighted Kogge-Stone over 24 lanes ----------------
__device__ __forceinline__ void scan_block(
    float xv, float& s_own, float& lev, float lev_a, float seas_b, float omb,
    float p1, float p2, float p4, float p8, float wrow, float myp)
{
    float ar  = lev_a * (xv * frcp(s_own));
    float acc = ar;
    acc = __builtin_fmaf(p1, dpp_z<0x111>(acc), acc);    // row_shr:1
    acc = __builtin_fmaf(p2, dpp_z<0x112>(acc), acc);    // row_shr:2
    acc = __builtin_fmaf(p4, dpp_z<0x114>(acc), acc);    // row_shr:4
    acc = __builtin_fmaf(p8, dpp_z<0x118>(acc), acc);    // row_shr:8
    acc = __builtin_fmaf(wrow, dpp_bcast15_z(acc), acc); // cross-row (lanes 16..23)
    float lv = __builtin_fmaf(myp, lev, acc);            // lev after own step
    float ns = __builtin_fmaf(omb, s_own, seas_b * (xv * frcp(lv)));
    s_own = ns;                                          // lanes >= 24: harmless junk
    lev = readlane_f(lv, 23);                            // block carry (step 23 = slot 0)
}

// ---------------- Phase 1: slot-parallel DPP scan (one wave/series), ~8 us -------------
__global__ __launch_bounds__(64, 1) void scan_phase1(
    const float* __restrict__ x, const float* __restrict__ lev_sms,
    const float* __restrict__ seas_sms, const float* __restrict__ seasonalities,
    const int* __restrict__ idxs, float* __restrict__ state)
{
    int b    = blockIdx.x;
    int lane = threadIdx.x;
    const float* xr = x + (size_t)b * T_;

    int id = idxs[b];
    float lev_a  = 1.0f / (1.0f + __expf(-lev_sms[id]));
    float seas_b = 1.0f / (1.0f + __expf(-seas_sms[id]));
    float oma = 1.0f - lev_a, omb = 1.0f - seas_b;

    float p1 = oma, p2 = p1 * p1, p4 = p2 * p2, p8 = p4 * p4, p16 = p8 * p8;
    int lp1 = lane + 1;
    float myp = ((lp1 & 1)  ? p1  : 1.0f) * ((lp1 & 2)  ? p2  : 1.0f)
              * ((lp1 & 4)  ? p4  : 1.0f) * ((lp1 & 8)  ? p8  : 1.0f)
              * ((lp1 & 16) ? p16 : 1.0f);           // oma^(lane+1)
    int e = lane - 15;
    float wrow = 0.0f;
    if (e > 0) {
        wrow = ((e & 1) ? p1 : 1.0f) * ((e & 2) ? p2 : 1.0f)
             * ((e & 4) ? p4 : 1.0f) * ((e & 8) ? p8 : 1.0f);   // oma^(lane-15)
    }

    int pos_own = (lane + 1 < 24) ? (lane + 1) : 0;
    float s_own = 1.0f;
    if (lane < 24) s_own = __expf(seasonalities[id * SEAS_ + pos_own]);

    float s0  = readlane_f(s_own, 23);
    float lev = xr[0] * frcp(s0);                    // lev0

    float xA0 = xr[1 +   0 + lane], xA1 = xr[1 +  24 + lane], xA2 = xr[1 +  48 + lane],
          xA3 = xr[1 +  72 + lane], xA4 = xr[1 +  96 + lane];
    float xB0 = xr[1 + 120 + lane], xB1 = xr[1 + 144 + lane], xB2 = xr[1 + 168 + lane],
          xB3 = xr[1 + 192 + lane], xB4 = xr[1 + 216 + lane];

    for (int g = 0; g < 16; g += 2) {
        int baseA = 1 + 5 * (g + 2) * 24 + lane;
        scan_block(xA0, s_own, lev, lev_a, seas_b, omb, p1, p2, p4, p8, wrow, myp);
        { int t = baseA;      xA0 = xr[t > 2047 ? 2047 : t]; }
        scan_block(xA1, s_own, lev, lev_a, seas_b, omb, p1, p2, p4, p8, wrow, myp);
        { int t = baseA + 24; xA1 = xr[t > 2047 ? 2047 : t]; }
        scan_block(xA2, s_own, lev, lev_a, seas_b, omb, p1, p2, p4, p8, wrow, myp);
        { int t = baseA + 48; xA2 = xr[t > 2047 ? 2047 : t]; }
        scan_block(xA3, s_own, lev, lev_a, seas_b, omb, p1, p2, p4, p8, wrow, myp);
        { int t = baseA + 72; xA3 = xr[t > 2047 ? 2047 : t]; }
        scan_block(xA4, s_own, lev, lev_a, seas_b, omb, p1, p2, p4, p8, wrow, myp);
        { int t = baseA + 96; xA4 = xr[t > 2047 ? 2047 : t]; }
        {   float* st = state + ((size_t)g * B_ + b) * 25;       // t = 120(g+1)
            if (lane < 24) st[pos_own] = s_own;
            if (lane == 24) st[24] = lev;
        }
        int baseB = 1 + 5 * (g + 3) * 24 + lane;
        scan_block(xB0, s_own, lev, lev_a, seas_b, omb, p1, p2, p4, p8, wrow, myp);
        { int t = baseB;      xB0 = xr[t > 2047 ? 2047 : t]; }
        scan_block(xB1, s_own, lev, lev_a, seas_b, omb, p1, p2, p4, p8, wrow, myp);
        { int t = baseB + 24; xB1 = xr[t > 2047 ? 2047 : t]; }
        scan_block(xB2, s_own, lev, lev_a, seas_b, omb, p1, p2, p4, p8, wrow, myp);
        { int t = baseB + 48; xB2 = xr[t > 2047 ? 2047 : t]; }
        scan_block(xB3, s_own, lev, lev_a, seas_b, omb, p1, p2, p4, p8, wrow, myp);
        { int t = baseB + 72; xB3 = xr[t > 2047 ? 2047 : t]; }
        scan_block(xB4, s_own, lev, lev_a, seas_b, omb, p1, p2, p4, p8, wrow, myp);
        { int t = baseB + 96; xB4 = xr[t > 2047 ? 2047 : t]; }
        {   float* st = state + ((size_t)(g + 1) * B_ + b) * 25; // t = 120(g+2)
            if (lane < 24) st[pos_own] = s_own;
            if (lane == 24) st[24] = lev;
        }
    }
}

// One 24-step block; writes levT global col + LDS tile rows (lev, ns). ILP-exposed.
__device__ __forceinline__ void es_block24_lds(
    const float4* __restrict__ xv, float* __restrict__ s,
    float lev_a, float oma, float seas_b, float omb, float& lev,
    float* __restrict__ levp, float* __restrict__ lrow, float* __restrict__ nrow)
{
    float ar[24], lv[24];
    #pragma unroll
    for (int j = 0; j < 24; ++j) {
        const int e = j + 1, pos = (j + 1 < 24) ? (j + 1) : 0;
        ar[j] = lev_a * (getc(xv[e >> 2], e & 3) * frcp(s[pos]));
    }
    #pragma unroll
    for (int j = 0; j < 24; ++j) {                   // serial lev chain
        lev = __builtin_fmaf(oma, lev, ar[j]);
        lv[j] = lev;
    }
    #pragma unroll
    for (int j = 0; j < 24; ++j) {                   // independent seasonal updates
        const int e = j + 1, pos = (j + 1 < 24) ? (j + 1) : 0;
        float xi = getc(xv[e >> 2], e & 3);
        float ns = __builtin_fmaf(omb, s[pos], seas_b * (xi * frcp(lv[j])));
        s[pos] = ns;
        levp[(size_t)j * B_] = lv[j];                // levT [t][b] (for msld)
        lrow[j] = lv[j];                             // LDS tiles (for b-major writes)
        nrow[j] = ns;
    }
}

// ---------------- Phase 2: 17 exact chunks; writes levT + out_levs/out_seas directly ---
__global__ __launch_bounds__(64, 1) void scan_phase2(
    const float* __restrict__ x, const float* __restrict__ lev_sms,
    const float* __restrict__ seas_sms, const float* __restrict__ seasonalities,
    const int* __restrict__ idxs, const float* __restrict__ state,
    float* __restrict__ levT, float* __restrict__ out_levs,
    float* __restrict__ out_seas)
{
    __shared__ float lev_lds[64][129];
    __shared__ float ns_lds[64][129];
    int tid = threadIdx.x;
    int b = blockIdx.x * 64 + tid;
    int c = blockIdx.y;
    const float4* xr4 = (const float4*)(x + (size_t)b * T_);

    int id = idxs[b];
    float lev_a  = 1.0f / (1.0f + __expf(-lev_sms[id]));
    float seas_b = 1.0f / (1.0f + __expf(-seas_sms[id]));
    float oma = 1.0f - lev_a, omb = 1.0f - seas_b;

    float s[SEAS_];
    float lev;
    if (c == 0) {
        #pragma unroll
        for (int j = 0; j < SEAS_; ++j) s[j] = __expf(seasonalities[id * SEAS_ + j]);
        #pragma unroll
        for (int j = 0; j < SEAS_; ++j) ns_lds[tid][j] = s[j];
        ns_lds[tid][24] = s[0];
        __syncthreads();
        for (int r = 0; r < 64; ++r) {
            int bb = blockIdx.x * 64 + r;
            if (tid < 25) out_seas[(size_t)bb * SFW_ + tid] = ns_lds[r][tid];
        }
        __syncthreads();
        lev = getc(xr4[0], 0) * frcp(s[0]);              // lev0
        levT[b] = lev;                                   // row 0 (msld)
        out_levs[(size_t)b * T_] = lev;                  // t = 0
    } else {
        const float* st = state + ((size_t)(c - 1) * B_ + b) * 25;
        #pragma unroll
        for (int j = 0; j < SEAS_; ++j) s[j] = st[j];
        lev = st[24];
    }

    float4 xv[7], xn[7];
    const float4* base0 = xr4 + 30 * c;                  // t = 120c ..
    #pragma unroll
    for (int q = 0; q < 7; ++q) xv[q] = base0[q];

    float* levp = levT + (size_t)(120 * c + 1) * B_ + b;

    #pragma unroll
    for (int kb = 0; kb < 5; ++kb) {                     // 5 blocks of 24 steps
        const float4* nb = xr4 + 30 * c + 6 * (kb + 1);
        if (c == NCH_ - 1 && kb == 4) {                  // next base 510: only 2 in-bounds
            xn[0] = nb[0]; xn[1] = nb[1];
        } else {
            #pragma unroll
            for (int q = 0; q < 7; ++q) xn[q] = nb[q];
        }
        es_block24_lds(xv, s, lev_a, oma, seas_b, omb, lev, levp,
                       &lev_lds[tid][kb * 24], &ns_lds[tid][kb * 24]);
        levp += (size_t)24 * B_;
        #pragma unroll
        for (int q = 0; q < 7; ++q) xv[q] = xn[q];
    }
    if (c == NCH_ - 1) {                                 // tail t = 2041..2047, cols 120+
        #pragma unroll
        for (int j = 0; j < 7; ++j) {
            const int e = j + 1, pos = j + 1;
            float xi    = getc(xv[e >> 2], e & 3);
            float ratio = xi * frcp(s[pos]);
            float nl    = __builtin_fmaf(oma, lev, lev_a * ratio);
            float ns    = __builtin_fmaf(omb, s[pos], seas_b * (xi * frcp(nl)));
            s[pos] = ns;
            lev = nl;
            levp[0] = nl;  levp += B_;
            lev_lds[tid][120 + j] = nl;
            ns_lds[tid][120 + j]  = ns;
        }
    }

    __syncthreads();
    int tb = 120 * c + 1;
    int NT = (c == NCH_ - 1) ? 127 : 120;
    for (int r = 0; r < 64; ++r) {
        int bb = blockIdx.x * 64 + r;
        float* ol = out_levs + (size_t)bb * T_ + tb;
        float* os = out_seas + (size_t)bb * SFW_ + tb + 24;
        ol[tid] = lev_lds[r][tid];
        os[tid] = ns_lds[r][tid];
        int t2 = tid + 64;
        if (t2 < NT) {
            ol[t2] = lev_lds[r][t2];
            os[t2] = ns_lds[r][t2];
        }
        if (c == NCH_ - 1 && tid < 24)                   // seasonal tail repeat
            out_seas[(size_t)bb * SFW_ + 2072 + tid] = ns_lds[r][103 + tid];
    }
}

// ---------------- mega: tiled win (32w x 8b per block, LDS-staged) + msld --------------
__global__ __launch_bounds__(256) void mega_kernel(
    const float* __restrict__ x, const float* __restrict__ levs,
    const float* __restrict__ seasF, const float* __restrict__ info_cat,
    const float* __restrict__ levT, vf4* __restrict__ out4,
    float* __restrict__ out_msld)
{
    int bid = blockIdx.x;
    int tid = threadIdx.x;
    if (bid < NWIN_) {                               // ---------------- win role
        __shared__ float x_t[BT_][57];               // t in [w0, w0+55]
        __shared__ float s_t[BT_][57];
        __shared__ float l_t[BT_][33];               // levs[b][w0+23+w], w in [0,32)
        __shared__ float ic[BT_][8];                 // info_cat (6 used)
        __shared__ __align__(16) vf2 ob[WT_][120];   // out staging: 32 w x 120 f2

        int wt = bid / NBT_;
        int bt = bid - wt * NBT_;
        int w0 = wt * WT_;                           // multiple of 32 -> f4-aligned
        int b0 = bt * BT_;

        // ---- load phase ----
        if (tid < 112) {                             // x: 8 rows x 14 f4
            int b = tid / 14, q = tid - b * 14;
            vf4 v = ((const vf4*)(x + (size_t)(b0 + b) * T_ + w0))[q];
            x_t[b][4 * q + 0] = v.x; x_t[b][4 * q + 1] = v.y;
            x_t[b][4 * q + 2] = v.z; x_t[b][4 * q + 3] = v.w;
        } else if (tid < 224) {                      // seas: 8 rows x 14 f4
            int t2 = tid - 112;
            int b = t2 / 14, q = t2 - b * 14;
            vf4 v = ((const vf4*)(seasF + (size_t)(b0 + b) * SFW_ + w0))[q];
            s_t[b][4 * q + 0] = v.x; s_t[b][4 * q + 1] = v.y;
            s_t[b][4 * q + 2] = v.z; s_t[b][4 * q + 3] = v.w;
        }
        {                                            // levs: 8 rows x 32 (scalar)
            int b = tid >> 5, w = tid & 31;
            l_t[b][w] = levs[(size_t)(b0 + b) * T_ + w0 + w + 23];
        }
        if (tid < 48) {                              // info_cat: 8 x 6
            int b = tid / 6, cc = tid - b * 6;
            ic[b][cc] = info_cat[(b0 + b) * C_ + cc];
        }
        __syncthreads();

        // ---- compute phase: one (w, b) pair per thread ----
        int w_l = tid >> 3, b_l = tid & 7;
        if (w0 + w_l < W_) {
            float inv = frcp(l_t[b_l][w_l]);
            vf2* obr = &ob[w_l][b_l * 15];
            #pragma unroll
            for (int j = 0; j < 12; ++j) {
                int t = w_l + 2 * j;
                vf2 v;
                v.x = x_t[b_l][t]     * frcp(s_t[b_l][t])     * inv;
                v.y = x_t[b_l][t + 1] * frcp(s_t[b_l][t + 1]) * inv;
                obr[j] = v;
            }
            #pragma unroll
            for (int j = 12; j < 15; ++j) {
                int cc = 2 * (j - 12);
                vf2 v;
                v.x = ic[b_l][cc];
                v.y = ic[b_l][cc + 1];
                obr[j] = v;
            }
        }
        __syncthreads();

        // ---- store phase: 1920 contiguous f4 per block, nontemporal ----
        const vf4* obf4 = (const vf4*)ob;            // row w_l = f4 [60*w_l, 60*w_l+60)
        #pragma unroll
        for (int k = 0; k < 8; ++k) {
            int g = tid + k * 256;
            if (g < 1920) {
                int w_l2 = g / 60, q = g - w_l2 * 60;
                if (w0 + w_l2 < W_) {
                    __builtin_nontemporal_store(
                        obf4[g], &out4[(size_t)(w0 + w_l2) * 7680 + bt * 60 + q]);
                }
            }
        }
    } else {                                         // ---------------- msld role
        int i = bid - NWIN_;                         // 0..2045
        const float* r0 = levT + (size_t)i * B_;
        float ssum = 0.0f;
        #pragma unroll
        for (int r = 0; r < 4; ++r) {
            int b = tid + 256 * r;
            float l0 = __logf(r0[b]);
            float l1 = __logf(r0[b + B_]);
            float l2 = __logf(r0[b + 2 * B_]);
            float d  = l2 - 2.0f * l1 + l0;
            ssum = __builtin_fmaf(d, d, ssum);
        }
        #pragma unroll
        for (int off = 32; off > 0; off >>= 1) ssum += __shfl_down(ssum, off);
        __shared__ float partial[4];
        int wid = tid >> 6;
        if ((tid & 63) == 0) partial[wid] = ssum;
        __syncthreads();
        if (tid == 0)
            out_msld[i] = (partial[0] + partial[1] + partial[2] + partial[3])
                          * (1.0f / 1024.0f);
    }
}

extern "C" void kernel_launch(void* const* d_in, const int* in_sizes, int n_in,
                              void* d_out, int out_size, void* d_ws, size_t ws_size,
                              hipStream_t stream)
{
    const float* train    = (const float*)d_in[0];
    const float* info_cat = (const float*)d_in[3];
    const float* lev_sms  = (const float*)d_in[4];
    const float* seas_sms = (const float*)d_in[5];
    const float* seasonal = (const float*)d_in[6];
    const int*   idxs     = (const int*)d_in[7];

    float* out      = (float*)d_out;
    float* out_ib   = out;                               // W*B*30
    float* out_levs = out + (size_t)W_ * B_ * 30;        // B*2048
    float* out_seas = out_levs + (size_t)B_ * T_;        // B*2096
    float* out_msld = out_seas + (size_t)B_ * SFW_;      // 2046

    float* ws   = (float*)d_ws;
    float* levT = ws;                                    // 2048*1024 floats

    // Exact boundary states in the head of out_ib: written by phase1, read by phase2,
    // later overwritten by mega's win blocks (stream-ordered, race-free).
    float* state = out_ib;                               // 16*1024*25 floats (1.6 MB)

    scan_phase1<<<B_, 64, 0, stream>>>(train, lev_sms, seas_sms, seasonal, idxs, state);

    scan_phase2<<<dim3(B_ / 64, NCH_), 64, 0, stream>>>(train, lev_sms, seas_sms,
                                                        seasonal, idxs, state,
                                                        levT, out_levs, out_seas);

    mega_kernel<<<NWIN_ + 2046, 256, 0, stream>>>(
        train, out_levs, out_seas, info_cat, levT, (vf4*)out_ib, out_msld);
}